// Round 4
// baseline (1143.575 us; speedup 1.0000x reference)
//
#include <hip/hip_runtime.h>

// GCN 2-layer, fp32, bucket-binned push aggregation (no global fp32 atomics, no CSR fill):
//   h   = relu(segsum_dst((x@W1)[src1] * w1))      128 -> 64
//   out = segsum_dst((h@W2)[src2] * w2)            64 -> 16
// N=100000, E=1600000. Buckets of 256 dst nodes (bucket = dst>>8, NB=391).
// Edge record packed int2: .x = src | (dst&255)<<20  (src<2^17 fits), .y = bits of w.

#define EPB 4096     // edges per binning block
#define NBMAX 512    // max buckets supported (N <= 131072)

// ---------------- dense layers ----------------

__global__ void gemm1_kernel(const float* __restrict__ x,
                             const float* __restrict__ W1,
                             float* __restrict__ h1, int n_nodes) {
    __shared__ float Wf[128 * 64];   // 32 KB
    __shared__ float xf[8 * 128];
    int tid = threadIdx.x;
    const float4* W4 = reinterpret_cast<const float4*>(W1);
    float4* Wf4 = reinterpret_cast<float4*>(Wf);
    for (int i = tid; i < 128 * 64 / 4; i += 256) Wf4[i] = W4[i];
    int node0 = blockIdx.x * 8;
    for (int i = tid; i < 8 * 128; i += 256) {
        int n = node0 + (i >> 7);
        xf[i] = (n < n_nodes) ? x[(size_t)n * 128 + (i & 127)] : 0.f;
    }
    __syncthreads();
    int w = tid >> 6, f = tid & 63;
    int nl0 = w * 2, nl1 = nl0 + 1;
    float acc0 = 0.f, acc1 = 0.f;
#pragma unroll 8
    for (int k = 0; k < 128; ++k) {
        float wv = Wf[k * 64 + f];
        acc0 += xf[nl0 * 128 + k] * wv;
        acc1 += xf[nl1 * 128 + k] * wv;
    }
    int n0 = node0 + nl0, n1 = node0 + nl1;
    if (n0 < n_nodes) h1[(size_t)n0 * 64 + f] = acc0;
    if (n1 < n_nodes) h1[(size_t)n1 * 64 + f] = acc1;
}

__global__ void gemm2_kernel(const float* __restrict__ agg1,
                             const float* __restrict__ W2,
                             float* __restrict__ h2, int n_nodes) {
    __shared__ float Wf[64 * 16];
    __shared__ float xf[16 * 65];
    int tid = threadIdx.x;
    for (int i = tid; i < 64 * 16; i += 256) Wf[i] = W2[i];
    int node0 = blockIdx.x * 16;
    for (int i = tid; i < 16 * 64; i += 256) {
        int nl = i >> 6, k = i & 63;
        int n = node0 + nl;
        xf[nl * 65 + k] = (n < n_nodes) ? agg1[(size_t)n * 64 + k] : 0.f;  // relu already applied
    }
    __syncthreads();
    int nl = tid >> 4, f = tid & 15;
    float acc = 0.f;
#pragma unroll 8
    for (int k = 0; k < 64; ++k) acc += xf[nl * 65 + k] * Wf[k * 16 + f];
    int n = node0 + nl;
    if (n < n_nodes) h2[(size_t)n * 16 + f] = acc;
}

// ---------------- edge binning ----------------

__global__ void bin_hist_kernel(const int* __restrict__ ei, int* __restrict__ hist_g,
                                int n_edges, int nblk, int nb) {
    __shared__ int hist[NBMAX];
    int tid = threadIdx.x, blk = blockIdx.x;
    for (int i = tid; i < nb; i += 256) hist[i] = 0;
    __syncthreads();
    int e0 = blk * EPB;
#pragma unroll
    for (int j = 0; j < EPB / 256; ++j) {
        int e = e0 + tid + j * 256;
        if (e < n_edges) atomicAdd(&hist[ei[n_edges + e] >> 8], 1);
    }
    __syncthreads();
    for (int i = tid; i < nb; i += 256) hist_g[i * nblk + blk] = hist[i];  // bucket-major
}

__global__ void scan_local_k(int* __restrict__ data, int* __restrict__ bsums, int n) {
    __shared__ int tmp[1024];
    int i = blockIdx.x * 1024 + threadIdx.x;
    int v = (i < n) ? data[i] : 0;
    tmp[threadIdx.x] = v;
    __syncthreads();
    for (int off = 1; off < 1024; off <<= 1) {
        int t = (threadIdx.x >= off) ? tmp[threadIdx.x - off] : 0;
        __syncthreads();
        tmp[threadIdx.x] += t;
        __syncthreads();
    }
    if (i < n) data[i] = tmp[threadIdx.x] - v;   // exclusive, in place
    if (threadIdx.x == 1023) bsums[blockIdx.x] = tmp[1023];
}

__global__ void scan_top_k(int* __restrict__ bsums, int nbk) {
    __shared__ int tmp[512];
    int v = (threadIdx.x < nbk) ? bsums[threadIdx.x] : 0;
    tmp[threadIdx.x] = v;
    __syncthreads();
    for (int off = 1; off < 512; off <<= 1) {
        int t = (threadIdx.x >= off) ? tmp[threadIdx.x - off] : 0;
        __syncthreads();
        tmp[threadIdx.x] += t;
        __syncthreads();
    }
    if (threadIdx.x < nbk) bsums[threadIdx.x] = tmp[threadIdx.x] - v;  // exclusive
}

__global__ void add_offsets_k(int* __restrict__ data, const int* __restrict__ bsums, int n) {
    int i = blockIdx.x * 1024 + threadIdx.x;
    if (i < n) data[i] += bsums[blockIdx.x];
}

__global__ void bin_scatter_kernel(const int* __restrict__ ei, const float* __restrict__ ew,
                                   const int* __restrict__ scan_g, int2* __restrict__ rec_out,
                                   int n_edges, int nblk, int nb) {
    __shared__ int2 srec[EPB];               // 32 KB
    __shared__ unsigned short sbkt[EPB];     // 8 KB
    __shared__ int hist[NBMAX], loff[NBMAX], cur[NBMAX], gbase[NBMAX];  // 8 KB
    __shared__ int p[256];
    int tid = threadIdx.x, blk = blockIdx.x;
    int e0 = blk * EPB;
    int cnt = min(EPB, n_edges - e0);
    for (int i = tid; i < nb; i += 256) hist[i] = 0;
    __syncthreads();
#pragma unroll
    for (int j = 0; j < EPB / 256; ++j) {
        int e = e0 + tid + j * 256;
        if (e < n_edges) atomicAdd(&hist[ei[n_edges + e] >> 8], 1);
    }
    __syncthreads();
    // exclusive scan of hist[0..nb) -> loff  (2 buckets per thread + Hillis-Steele over partials)
    int b0 = tid * 2;
    int c0 = (b0 < nb) ? hist[b0] : 0;
    int c1 = (b0 + 1 < nb) ? hist[b0 + 1] : 0;
    p[tid] = c0 + c1;
    __syncthreads();
    for (int off = 1; off < 256; off <<= 1) {
        int t = (tid >= off) ? p[tid - off] : 0;
        __syncthreads();
        p[tid] += t;
        __syncthreads();
    }
    int base = (tid > 0) ? p[tid - 1] : 0;
    if (b0 < nb)     { loff[b0] = base;         cur[b0] = base; }
    if (b0 + 1 < nb) { loff[b0 + 1] = base + c0; cur[b0 + 1] = base + c0; }
    for (int i = tid; i < nb; i += 256) gbase[i] = scan_g[i * nblk + blk];
    __syncthreads();
    // rank + stage (LDS counting sort by bucket)
#pragma unroll
    for (int j = 0; j < EPB / 256; ++j) {
        int e = e0 + tid + j * 256;
        if (e < n_edges) {
            int s = ei[e], d = ei[n_edges + e];
            int b = d >> 8;
            int r = atomicAdd(&cur[b], 1);
            srec[r] = make_int2(s | ((d & 255) << 20), __float_as_int(ew[e]));
            sbkt[r] = (unsigned short)b;
        }
    }
    __syncthreads();
    // coalesced run writes
    for (int i = tid; i < cnt; i += 256) {
        int b = sbkt[i];
        rec_out[gbase[b] + (i - loff[b])] = srec[i];
    }
}

// ---------------- per-bucket LDS-tile aggregation ----------------

__global__ __launch_bounds__(512) void agg1_kernel(const float* __restrict__ h1,
                                                   const int2* __restrict__ rec,
                                                   const int* __restrict__ scan_g,
                                                   float* __restrict__ agg,
                                                   int n_nodes, int n_edges, int nblk, int nb) {
    __shared__ float tile[256 * 64];   // 64 KB
    int tid = threadIdx.x, b = blockIdx.x;
    for (int i = tid; i < 256 * 64; i += 512) tile[i] = 0.f;
    int start = scan_g[b * nblk];
    int end = (b + 1 < nb) ? scan_g[(b + 1) * nblk] : n_edges;
    __syncthreads();
    int wave = tid >> 6, lane = tid & 63;
    int e = start + wave;
    for (; e + 8 < end; e += 16) {                 // 2-wide: two rows in flight
        int2 r0 = rec[e];
        int2 r1 = rec[e + 8];
        float v0 = h1[(size_t)(r0.x & 0xFFFFF) * 64 + lane];
        float v1 = h1[(size_t)(r1.x & 0xFFFFF) * 64 + lane];
        atomicAdd(&tile[((r0.x >> 20) & 255) * 64 + lane], v0 * __int_as_float(r0.y));
        atomicAdd(&tile[((r1.x >> 20) & 255) * 64 + lane], v1 * __int_as_float(r1.y));
    }
    if (e < end) {
        int2 r0 = rec[e];
        float v0 = h1[(size_t)(r0.x & 0xFFFFF) * 64 + lane];
        atomicAdd(&tile[((r0.x >> 20) & 255) * 64 + lane], v0 * __int_as_float(r0.y));
    }
    __syncthreads();
    int node0 = b << 8;
    for (int i = tid; i < 256 * 64; i += 512) {
        int n = node0 + (i >> 6);
        if (n < n_nodes) agg[(size_t)n * 64 + (i & 63)] = fmaxf(tile[i], 0.f);  // fused relu
    }
}

__global__ __launch_bounds__(512) void agg2_kernel(const float* __restrict__ h2,
                                                   const int2* __restrict__ rec,
                                                   const int* __restrict__ scan_g,
                                                   float* __restrict__ out,
                                                   int n_nodes, int n_edges, int nblk, int nb) {
    __shared__ float tile[256 * 16];   // 16 KB
    int tid = threadIdx.x, b = blockIdx.x;
    for (int i = tid; i < 256 * 16; i += 512) tile[i] = 0.f;
    int start = scan_g[b * nblk];
    int end = (b + 1 < nb) ? scan_g[(b + 1) * nblk] : n_edges;
    __syncthreads();
    int wave = tid >> 6, lane = tid & 63;
    int sub = lane >> 4, fl = lane & 15;           // 4 edges per wave-iteration
    for (int e0 = start + wave * 4; e0 < end; e0 += 32) {
        int e = e0 + sub;
        if (e < end) {
            int2 r = rec[e];
            float v = h2[(size_t)(r.x & 0xFFFFF) * 16 + fl];
            atomicAdd(&tile[((r.x >> 20) & 255) * 16 + fl], v * __int_as_float(r.y));
        }
    }
    __syncthreads();
    int node0 = b << 8;
    for (int i = tid; i < 256 * 16; i += 512) {
        int n = node0 + (i >> 4);
        if (n < n_nodes) out[(size_t)n * 16 + (i & 15)] = tile[i];
    }
}

// ---------------- launch ----------------

extern "C" void kernel_launch(void* const* d_in, const int* in_sizes, int n_in,
                              void* d_out, int out_size, void* d_ws, size_t ws_size,
                              hipStream_t stream) {
    const float* x   = (const float*)d_in[0];
    const int*   ei1 = (const int*)d_in[1];
    const int*   ei2 = (const int*)d_in[2];
    const float* ew1 = (const float*)d_in[3];
    const float* ew2 = (const float*)d_in[4];
    const float* W1  = (const float*)d_in[5];
    const float* W2  = (const float*)d_in[6];

    const int n_nodes = in_sizes[0] / 128;          // 100000
    const int n_edges = in_sizes[1] / 2;            // 1600000
    const int nb   = (n_nodes + 255) >> 8;          // 391 buckets
    const int nblk = (n_edges + EPB - 1) / EPB;     // 391 binning blocks
    const int n_scan = nb * nblk;                   // 152881
    const int scan_blocks = (n_scan + 1023) / 1024; // 150

    // ws layout (4-byte units)
    float* h1     = (float*)d_ws;                        // N*64
    float* agg1   = h1 + (size_t)n_nodes * 64;           // N*64
    float* h2     = agg1 + (size_t)n_nodes * 64;         // N*16
    int2*  recbuf = (int2*)(h2 + (size_t)n_nodes * 16);  // E int2 (reused both layers)
    int*   hist_g = (int*)(recbuf + n_edges);            // nb*nblk
    int*   bsums  = hist_g + n_scan;                     // 512
    float* out    = (float*)d_out;

    // ---- layer 1 ----
    gemm1_kernel<<<(n_nodes + 7) / 8, 256, 0, stream>>>(x, W1, h1, n_nodes);
    bin_hist_kernel<<<nblk, 256, 0, stream>>>(ei1, hist_g, n_edges, nblk, nb);
    scan_local_k<<<scan_blocks, 1024, 0, stream>>>(hist_g, bsums, n_scan);
    scan_top_k<<<1, 512, 0, stream>>>(bsums, scan_blocks);
    add_offsets_k<<<scan_blocks, 1024, 0, stream>>>(hist_g, bsums, n_scan);
    bin_scatter_kernel<<<nblk, 256, 0, stream>>>(ei1, ew1, hist_g, recbuf, n_edges, nblk, nb);
    agg1_kernel<<<nb, 512, 0, stream>>>(h1, recbuf, hist_g, agg1, n_nodes, n_edges, nblk, nb);

    // ---- layer 2 ----
    gemm2_kernel<<<(n_nodes + 15) / 16, 256, 0, stream>>>(agg1, W2, h2, n_nodes);
    bin_hist_kernel<<<nblk, 256, 0, stream>>>(ei2, hist_g, n_edges, nblk, nb);
    scan_local_k<<<scan_blocks, 1024, 0, stream>>>(hist_g, bsums, n_scan);
    scan_top_k<<<1, 512, 0, stream>>>(bsums, scan_blocks);
    add_offsets_k<<<scan_blocks, 1024, 0, stream>>>(hist_g, bsums, n_scan);
    bin_scatter_kernel<<<nblk, 256, 0, stream>>>(ei2, ew2, hist_g, recbuf, n_edges, nblk, nb);
    agg2_kernel<<<nb, 512, 0, stream>>>(h2, recbuf, hist_g, out, n_nodes, n_edges, nblk, nb);
}

// Round 5
// 418.387 us; speedup vs baseline: 2.7333x; 2.7333x over previous
//
#include <hip/hip_runtime.h>

// GCN 2-layer, fp32. Pipeline per layer:
//   gemm -> bin_hist/scan/bin_scatter (bucket-sort edges by dst>>8, coalesced writes)
//        -> bucket_sort (in-LDS counting sort by dst&255 -> full dst-sorted CSR + rowptr)
//        -> gather (wave-per-node, 4-wide ILP, no atomics)
// N=100000, E=1600000. Record int2: .x = src | (dst&255)<<20, .y = bits of w.

#define EPB 4096     // edges per binning block
#define NBMAX 512    // max buckets (N <= 131072)
#define CAP 6144     // max records per bucket (avg 4096, sigma ~64; 32-sigma headroom)

// ---------------- dense layers ----------------

__global__ void gemm1_kernel(const float* __restrict__ x,
                             const float* __restrict__ W1,
                             float* __restrict__ h1, int n_nodes) {
    __shared__ float Wf[128 * 64];   // 32 KB
    __shared__ float xf[8 * 128];
    int tid = threadIdx.x;
    const float4* W4 = reinterpret_cast<const float4*>(W1);
    float4* Wf4 = reinterpret_cast<float4*>(Wf);
    for (int i = tid; i < 128 * 64 / 4; i += 256) Wf4[i] = W4[i];
    int node0 = blockIdx.x * 8;
    for (int i = tid; i < 8 * 128; i += 256) {
        int n = node0 + (i >> 7);
        xf[i] = (n < n_nodes) ? x[(size_t)n * 128 + (i & 127)] : 0.f;
    }
    __syncthreads();
    int w = tid >> 6, f = tid & 63;
    int nl0 = w * 2, nl1 = nl0 + 1;
    float acc0 = 0.f, acc1 = 0.f;
#pragma unroll 8
    for (int k = 0; k < 128; ++k) {
        float wv = Wf[k * 64 + f];
        acc0 += xf[nl0 * 128 + k] * wv;
        acc1 += xf[nl1 * 128 + k] * wv;
    }
    int n0 = node0 + nl0, n1 = node0 + nl1;
    if (n0 < n_nodes) h1[(size_t)n0 * 64 + f] = acc0;
    if (n1 < n_nodes) h1[(size_t)n1 * 64 + f] = acc1;
}

__global__ void gemm2_kernel(const float* __restrict__ agg1,
                             const float* __restrict__ W2,
                             float* __restrict__ h2, int n_nodes) {
    __shared__ float Wf[64 * 16];
    __shared__ float xf[16 * 65];
    int tid = threadIdx.x;
    for (int i = tid; i < 64 * 16; i += 256) Wf[i] = W2[i];
    int node0 = blockIdx.x * 16;
    for (int i = tid; i < 16 * 64; i += 256) {
        int nl = i >> 6, k = i & 63;
        int n = node0 + nl;
        xf[nl * 65 + k] = (n < n_nodes) ? agg1[(size_t)n * 64 + k] : 0.f;  // relu already applied
    }
    __syncthreads();
    int nl = tid >> 4, f = tid & 15;
    float acc = 0.f;
#pragma unroll 8
    for (int k = 0; k < 64; ++k) acc += xf[nl * 65 + k] * Wf[k * 16 + f];
    int n = node0 + nl;
    if (n < n_nodes) h2[(size_t)n * 16 + f] = acc;
}

// ---------------- edge binning (bucket = dst>>8) ----------------

__global__ void bin_hist_kernel(const int* __restrict__ ei, int* __restrict__ hist_g,
                                int n_edges, int nblk, int nb) {
    __shared__ int hist[NBMAX];
    int tid = threadIdx.x, blk = blockIdx.x;
    for (int i = tid; i < nb; i += 256) hist[i] = 0;
    __syncthreads();
    int e0 = blk * EPB;
#pragma unroll
    for (int j = 0; j < EPB / 256; ++j) {
        int e = e0 + tid + j * 256;
        if (e < n_edges) atomicAdd(&hist[ei[n_edges + e] >> 8], 1);
    }
    __syncthreads();
    for (int i = tid; i < nb; i += 256) hist_g[i * nblk + blk] = hist[i];  // bucket-major
}

__global__ void scan_local_k(int* __restrict__ data, int* __restrict__ bsums, int n) {
    __shared__ int tmp[1024];
    int i = blockIdx.x * 1024 + threadIdx.x;
    int v = (i < n) ? data[i] : 0;
    tmp[threadIdx.x] = v;
    __syncthreads();
    for (int off = 1; off < 1024; off <<= 1) {
        int t = (threadIdx.x >= off) ? tmp[threadIdx.x - off] : 0;
        __syncthreads();
        tmp[threadIdx.x] += t;
        __syncthreads();
    }
    if (i < n) data[i] = tmp[threadIdx.x] - v;   // exclusive, in place
    if (threadIdx.x == 1023) bsums[blockIdx.x] = tmp[1023];
}

__global__ void scan_top_k(int* __restrict__ bsums, int nbk) {
    __shared__ int tmp[512];
    int v = (threadIdx.x < nbk) ? bsums[threadIdx.x] : 0;
    tmp[threadIdx.x] = v;
    __syncthreads();
    for (int off = 1; off < 512; off <<= 1) {
        int t = (threadIdx.x >= off) ? tmp[threadIdx.x - off] : 0;
        __syncthreads();
        tmp[threadIdx.x] += t;
        __syncthreads();
    }
    if (threadIdx.x < nbk) bsums[threadIdx.x] = tmp[threadIdx.x] - v;  // exclusive
}

__global__ void add_offsets_k(int* __restrict__ data, const int* __restrict__ bsums, int n) {
    int i = blockIdx.x * 1024 + threadIdx.x;
    if (i < n) data[i] += bsums[blockIdx.x];
}

__global__ void bin_scatter_kernel(const int* __restrict__ ei, const float* __restrict__ ew,
                                   const int* __restrict__ scan_g, int2* __restrict__ rec_out,
                                   int n_edges, int nblk, int nb) {
    __shared__ int2 srec[EPB];               // 32 KB
    __shared__ unsigned short sbkt[EPB];     // 8 KB
    __shared__ int hist[NBMAX], loff[NBMAX], cur[NBMAX], gbase[NBMAX];  // 8 KB
    __shared__ int p[256];
    int tid = threadIdx.x, blk = blockIdx.x;
    int e0 = blk * EPB;
    int cnt = min(EPB, n_edges - e0);
    for (int i = tid; i < nb; i += 256) hist[i] = 0;
    __syncthreads();
#pragma unroll
    for (int j = 0; j < EPB / 256; ++j) {
        int e = e0 + tid + j * 256;
        if (e < n_edges) atomicAdd(&hist[ei[n_edges + e] >> 8], 1);
    }
    __syncthreads();
    // exclusive scan of hist[0..nb) -> loff (2 buckets/thread + Hillis-Steele over partials)
    int b0 = tid * 2;
    int c0 = (b0 < nb) ? hist[b0] : 0;
    int c1 = (b0 + 1 < nb) ? hist[b0 + 1] : 0;
    p[tid] = c0 + c1;
    __syncthreads();
    for (int off = 1; off < 256; off <<= 1) {
        int t = (tid >= off) ? p[tid - off] : 0;
        __syncthreads();
        p[tid] += t;
        __syncthreads();
    }
    int base = (tid > 0) ? p[tid - 1] : 0;
    if (b0 < nb)     { loff[b0] = base;          cur[b0] = base; }
    if (b0 + 1 < nb) { loff[b0 + 1] = base + c0; cur[b0 + 1] = base + c0; }
    for (int i = tid; i < nb; i += 256) gbase[i] = scan_g[i * nblk + blk];
    __syncthreads();
    // rank + stage (LDS counting sort by bucket)
#pragma unroll
    for (int j = 0; j < EPB / 256; ++j) {
        int e = e0 + tid + j * 256;
        if (e < n_edges) {
            int s = ei[e], d = ei[n_edges + e];
            int b = d >> 8;
            int r = atomicAdd(&cur[b], 1);
            srec[r] = make_int2(s | ((d & 255) << 20), __float_as_int(ew[e]));
            sbkt[r] = (unsigned short)b;
        }
    }
    __syncthreads();
    // coalesced run writes
    for (int i = tid; i < cnt; i += 256) {
        int b = sbkt[i];
        rec_out[gbase[b] + (i - loff[b])] = srec[i];
    }
}

// ---------------- per-bucket node sort (-> full CSR + rowptr) ----------------

__global__ __launch_bounds__(256) void bucket_sort_kernel(
        const int2* __restrict__ rec_in, const int* __restrict__ scan_g,
        int2* __restrict__ rec_out, int* __restrict__ rowptr,
        int n_nodes, int n_edges, int nblk, int nb) {
    __shared__ int2 srec[CAP];               // 48 KB
    __shared__ int hist[256], cur[256], rp[256];
    int tid = threadIdx.x, b = blockIdx.x;
    int start = scan_g[b * nblk];
    int end = (b + 1 < nb) ? scan_g[(b + 1) * nblk] : n_edges;
    int cnt = end - start;
    hist[tid] = 0;
    __syncthreads();
    for (int i = tid; i < cnt; i += 256) {
        int2 r = rec_in[start + i];
        atomicAdd(&hist[(r.x >> 20) & 255], 1);
    }
    __syncthreads();
    int v = hist[tid];
    rp[tid] = v;
    __syncthreads();
    for (int off = 1; off < 256; off <<= 1) {
        int t = (tid >= off) ? rp[tid - off] : 0;
        __syncthreads();
        rp[tid] += t;
        __syncthreads();
    }
    int excl = rp[tid] - v;          // exclusive scan
    cur[tid] = excl;
    int node = (b << 8) + tid;
    if (node < n_nodes) rowptr[node] = start + excl;
    if (b == nb - 1 && tid == 0) rowptr[n_nodes] = n_edges;
    __syncthreads();
    // rank into LDS by dst&255 (re-read coalesced, L2-hot)
    for (int i = tid; i < cnt; i += 256) {
        int2 r = rec_in[start + i];
        int rk = atomicAdd(&cur[(r.x >> 20) & 255], 1);
        if (rk < CAP) srec[rk] = r;
    }
    __syncthreads();
    // coalesced write-out
    int lim = min(cnt, CAP);
    for (int i = tid; i < lim; i += 256) rec_out[start + i] = srec[i];
}

// ---------------- gather-side aggregation (wave-per-node, 4-wide ILP) ----------------

__global__ void gather1_kernel(const float* __restrict__ h1,
                               const int* __restrict__ rowptr,
                               const int2* __restrict__ rec,
                               float* __restrict__ agg, int n_nodes) {
    int n = blockIdx.x * 4 + (threadIdx.x >> 6);
    if (n >= n_nodes) return;
    int f = threadIdx.x & 63;
    int i = rowptr[n], end = rowptr[n + 1];
    float a0 = 0.f, a1 = 0.f, a2 = 0.f, a3 = 0.f;
    for (; i + 3 < end; i += 4) {
        int2 r0 = rec[i], r1 = rec[i + 1], r2 = rec[i + 2], r3 = rec[i + 3];
        a0 += h1[(size_t)(r0.x & 0xFFFFF) * 64 + f] * __int_as_float(r0.y);
        a1 += h1[(size_t)(r1.x & 0xFFFFF) * 64 + f] * __int_as_float(r1.y);
        a2 += h1[(size_t)(r2.x & 0xFFFFF) * 64 + f] * __int_as_float(r2.y);
        a3 += h1[(size_t)(r3.x & 0xFFFFF) * 64 + f] * __int_as_float(r3.y);
    }
    for (; i < end; ++i) {
        int2 r = rec[i];
        a0 += h1[(size_t)(r.x & 0xFFFFF) * 64 + f] * __int_as_float(r.y);
    }
    agg[(size_t)n * 64 + f] = fmaxf((a0 + a1) + (a2 + a3), 0.f);  // fused relu
}

__global__ void gather2_kernel(const float* __restrict__ h2,
                               const int* __restrict__ rowptr,
                               const int2* __restrict__ rec,
                               float* __restrict__ out, int n_nodes) {
    int n = blockIdx.x * 16 + (threadIdx.x >> 4);
    if (n >= n_nodes) return;
    int f = threadIdx.x & 15;
    int i = rowptr[n], end = rowptr[n + 1];
    float a0 = 0.f, a1 = 0.f, a2 = 0.f, a3 = 0.f;
    for (; i + 3 < end; i += 4) {
        int2 r0 = rec[i], r1 = rec[i + 1], r2 = rec[i + 2], r3 = rec[i + 3];
        a0 += h2[(size_t)(r0.x & 0xFFFFF) * 16 + f] * __int_as_float(r0.y);
        a1 += h2[(size_t)(r1.x & 0xFFFFF) * 16 + f] * __int_as_float(r1.y);
        a2 += h2[(size_t)(r2.x & 0xFFFFF) * 16 + f] * __int_as_float(r2.y);
        a3 += h2[(size_t)(r3.x & 0xFFFFF) * 16 + f] * __int_as_float(r3.y);
    }
    for (; i < end; ++i) {
        int2 r = rec[i];
        a0 += h2[(size_t)(r.x & 0xFFFFF) * 16 + f] * __int_as_float(r.y);
    }
    out[(size_t)n * 16 + f] = (a0 + a1) + (a2 + a3);
}

// ---------------- launch ----------------

extern "C" void kernel_launch(void* const* d_in, const int* in_sizes, int n_in,
                              void* d_out, int out_size, void* d_ws, size_t ws_size,
                              hipStream_t stream) {
    const float* x   = (const float*)d_in[0];
    const int*   ei1 = (const int*)d_in[1];
    const int*   ei2 = (const int*)d_in[2];
    const float* ew1 = (const float*)d_in[3];
    const float* ew2 = (const float*)d_in[4];
    const float* W1  = (const float*)d_in[5];
    const float* W2  = (const float*)d_in[6];

    const int n_nodes = in_sizes[0] / 128;          // 100000
    const int n_edges = in_sizes[1] / 2;            // 1600000
    const int nb   = (n_nodes + 255) >> 8;          // 391 buckets
    const int nblk = (n_edges + EPB - 1) / EPB;     // 391 binning blocks
    const int n_scan = nb * nblk;                   // 152881
    const int scan_blocks = (n_scan + 1023) / 1024; // 150

    // ws layout (4-byte units)
    float* h1     = (float*)d_ws;                        // N*64
    float* agg1   = h1 + (size_t)n_nodes * 64;           // N*64
    float* h2     = agg1 + (size_t)n_nodes * 64;         // N*16
    int2*  recbuf = (int2*)(h2 + (size_t)n_nodes * 16);  // E int2 (bucket-sorted)
    int2*  rec2   = recbuf + n_edges;                    // E int2 (node-sorted)
    int*   hist_g = (int*)(rec2 + n_edges);              // nb*nblk
    int*   bsums  = hist_g + n_scan;                     // 512
    int*   rowptr = bsums + 512;                         // N+1
    float* out    = (float*)d_out;

    // ---- layer 1 ----
    gemm1_kernel<<<(n_nodes + 7) / 8, 256, 0, stream>>>(x, W1, h1, n_nodes);
    bin_hist_kernel<<<nblk, 256, 0, stream>>>(ei1, hist_g, n_edges, nblk, nb);
    scan_local_k<<<scan_blocks, 1024, 0, stream>>>(hist_g, bsums, n_scan);
    scan_top_k<<<1, 512, 0, stream>>>(bsums, scan_blocks);
    add_offsets_k<<<scan_blocks, 1024, 0, stream>>>(hist_g, bsums, n_scan);
    bin_scatter_kernel<<<nblk, 256, 0, stream>>>(ei1, ew1, hist_g, recbuf, n_edges, nblk, nb);
    bucket_sort_kernel<<<nb, 256, 0, stream>>>(recbuf, hist_g, rec2, rowptr,
                                               n_nodes, n_edges, nblk, nb);
    gather1_kernel<<<(n_nodes + 3) / 4, 256, 0, stream>>>(h1, rowptr, rec2, agg1, n_nodes);

    // ---- layer 2 ----
    gemm2_kernel<<<(n_nodes + 15) / 16, 256, 0, stream>>>(agg1, W2, h2, n_nodes);
    bin_hist_kernel<<<nblk, 256, 0, stream>>>(ei2, hist_g, n_edges, nblk, nb);
    scan_local_k<<<scan_blocks, 1024, 0, stream>>>(hist_g, bsums, n_scan);
    scan_top_k<<<1, 512, 0, stream>>>(bsums, scan_blocks);
    add_offsets_k<<<scan_blocks, 1024, 0, stream>>>(hist_g, bsums, n_scan);
    bin_scatter_kernel<<<nblk, 256, 0, stream>>>(ei2, ew2, hist_g, recbuf, n_edges, nblk, nb);
    bucket_sort_kernel<<<nb, 256, 0, stream>>>(recbuf, hist_g, rec2, rowptr,
                                               n_nodes, n_edges, nblk, nb);
    gather2_kernel<<<(n_nodes + 15) / 16, 256, 0, stream>>>(h2, rowptr, rec2, out, n_nodes);
}

// Round 6
// 397.698 us; speedup vs baseline: 2.8755x; 1.0520x over previous
//
#include <hip/hip_runtime.h>

// GCN 2-layer, fp32. Pipeline per layer:
//   gemm (register-tiled) -> bin_hist/scan/bin_scatter (bucket-sort edges by dst>>8)
//        -> bucket_sort (in-LDS counting sort by dst&255 -> dst-sorted CSR + rowptr)
//        -> gather (wave-per-node, 4-wide ILP, no atomics)
// N=100000, E=1600000. Record int2: .x = src | (dst&255)<<20, .y = bits of w.

#define EPB 4096     // edges per binning block
#define NBMAX 512    // max buckets (N <= 131072)
#define CAP 6144     // max records per bucket (avg 4096; 32-sigma headroom)

// ---------------- dense layers (register-tiled, k-major LDS) ----------------

// gemm1: [N,128] @ [128,64] -> [N,64]. Block: 128 threads, tile 128 nodes x 64 feats.
// Thread: 8 nodes x 8 feats. K staged in 4 slabs of 32, k-major (As[k][n]).
__global__ __launch_bounds__(128) void gemm1_kernel(const float* __restrict__ x,
                                                    const float* __restrict__ W1,
                                                    float* __restrict__ h1, int n_nodes) {
    __shared__ float As[32][132];   // k-major, node-contiguous; pad 128->132 (~4-way stage writes)
    __shared__ float Bs[32][64];    // k-major, feat-contiguous
    int tid = threadIdx.x;
    int node0 = blockIdx.x * 128;
    int n8 = (tid & 15) * 8;        // node offset in tile
    int f8 = (tid >> 4) * 8;        // feat offset
    float acc[8][8];
#pragma unroll
    for (int i = 0; i < 8; ++i)
#pragma unroll
        for (int j = 0; j < 8; ++j) acc[i][j] = 0.f;

    const float4* x4 = reinterpret_cast<const float4*>(x);
    const float4* W4 = reinterpret_cast<const float4*>(W1);

    for (int s = 0; s < 4; ++s) {
        // stage As: x[node0+n][s*32 + k], transposed into As[k][n]
#pragma unroll
        for (int j = 0; j < 8; ++j) {
            int idx = tid + j * 128;            // 1024 float4 = 128n x 32k
            int n = idx >> 3;
            int kq = idx & 7;                   // k-quad 0..7
            float4 v = make_float4(0.f, 0.f, 0.f, 0.f);
            if (node0 + n < n_nodes) v = x4[(size_t)(node0 + n) * 32 + s * 8 + kq];
            int k4 = kq * 4;
            As[k4 + 0][n] = v.x;
            As[k4 + 1][n] = v.y;
            As[k4 + 2][n] = v.z;
            As[k4 + 3][n] = v.w;
        }
        // stage Bs: W1[s*32+k][f] (already k-major), float4 copy
#pragma unroll
        for (int j = 0; j < 4; ++j) {
            int idx = tid + j * 128;            // 512 float4 = 32k x 64f
            int k = idx >> 4;
            int fq = idx & 15;
            *reinterpret_cast<float4*>(&Bs[k][fq * 4]) = W4[(size_t)(s * 32 + k) * 16 + fq];
        }
        __syncthreads();
#pragma unroll
        for (int kk = 0; kk < 32; ++kk) {
            float4 a0 = *reinterpret_cast<const float4*>(&As[kk][n8]);
            float4 a1 = *reinterpret_cast<const float4*>(&As[kk][n8 + 4]);
            float4 b0 = *reinterpret_cast<const float4*>(&Bs[kk][f8]);
            float4 b1 = *reinterpret_cast<const float4*>(&Bs[kk][f8 + 4]);
            float av[8] = {a0.x, a0.y, a0.z, a0.w, a1.x, a1.y, a1.z, a1.w};
            float bv[8] = {b0.x, b0.y, b0.z, b0.w, b1.x, b1.y, b1.z, b1.w};
#pragma unroll
            for (int i = 0; i < 8; ++i)
#pragma unroll
                for (int j = 0; j < 8; ++j) acc[i][j] += av[i] * bv[j];
        }
        __syncthreads();
    }
#pragma unroll
    for (int i = 0; i < 8; ++i) {
        int n = node0 + n8 + i;
        if (n < n_nodes) {
            float4* dst = reinterpret_cast<float4*>(h1 + (size_t)n * 64 + f8);
            dst[0] = make_float4(acc[i][0], acc[i][1], acc[i][2], acc[i][3]);
            dst[1] = make_float4(acc[i][4], acc[i][5], acc[i][6], acc[i][7]);
        }
    }
}

// gemm2: relu already applied to agg1 by gather1. [N,64] @ [64,16] -> [N,16].
// Block: 128 threads, tile 128 nodes x 16 feats. Thread: 4 nodes x 4 feats. K in 2 slabs of 32.
__global__ __launch_bounds__(128) void gemm2_kernel(const float* __restrict__ agg1,
                                                    const float* __restrict__ W2,
                                                    float* __restrict__ h2, int n_nodes) {
    __shared__ float As[32][132];
    __shared__ float Bs[32][16];
    int tid = threadIdx.x;
    int node0 = blockIdx.x * 128;
    int n4 = (tid & 31) * 4;
    int f4 = (tid >> 5) * 4;
    float acc[4][4];
#pragma unroll
    for (int i = 0; i < 4; ++i)
#pragma unroll
        for (int j = 0; j < 4; ++j) acc[i][j] = 0.f;

    const float4* a4 = reinterpret_cast<const float4*>(agg1);
    const float4* W4 = reinterpret_cast<const float4*>(W2);

    for (int s = 0; s < 2; ++s) {
#pragma unroll
        for (int j = 0; j < 8; ++j) {
            int idx = tid + j * 128;            // 1024 float4 = 128n x 32k
            int n = idx >> 3;
            int kq = idx & 7;
            float4 v = make_float4(0.f, 0.f, 0.f, 0.f);
            if (node0 + n < n_nodes) v = a4[(size_t)(node0 + n) * 16 + s * 8 + kq];
            int k4 = kq * 4;
            As[k4 + 0][n] = v.x;
            As[k4 + 1][n] = v.y;
            As[k4 + 2][n] = v.z;
            As[k4 + 3][n] = v.w;
        }
        {
            int k = tid >> 2, fq = tid & 3;     // 128 float4 = 32k x 16f
            *reinterpret_cast<float4*>(&Bs[k][fq * 4]) = W4[(size_t)(s * 32 + k) * 4 + fq];
        }
        __syncthreads();
#pragma unroll
        for (int kk = 0; kk < 32; ++kk) {
            float4 a = *reinterpret_cast<const float4*>(&As[kk][n4]);
            float4 b = *reinterpret_cast<const float4*>(&Bs[kk][f4]);
            float av[4] = {a.x, a.y, a.z, a.w};
            float bv[4] = {b.x, b.y, b.z, b.w};
#pragma unroll
            for (int i = 0; i < 4; ++i)
#pragma unroll
                for (int j = 0; j < 4; ++j) acc[i][j] += av[i] * bv[j];
        }
        __syncthreads();
    }
#pragma unroll
    for (int i = 0; i < 4; ++i) {
        int n = node0 + n4 + i;
        if (n < n_nodes)
            *reinterpret_cast<float4*>(h2 + (size_t)n * 16 + f4) =
                make_float4(acc[i][0], acc[i][1], acc[i][2], acc[i][3]);
    }
}

// ---------------- edge binning (bucket = dst>>8) ----------------

__global__ void bin_hist_kernel(const int* __restrict__ ei, int* __restrict__ hist_g,
                                int n_edges, int nblk, int nb) {
    __shared__ int hist[NBMAX];
    int tid = threadIdx.x, blk = blockIdx.x;
    for (int i = tid; i < nb; i += 256) hist[i] = 0;
    __syncthreads();
    int e0 = blk * EPB;
#pragma unroll
    for (int j = 0; j < EPB / 256; ++j) {
        int e = e0 + tid + j * 256;
        if (e < n_edges) atomicAdd(&hist[ei[n_edges + e] >> 8], 1);
    }
    __syncthreads();
    for (int i = tid; i < nb; i += 256) hist_g[i * nblk + blk] = hist[i];  // bucket-major
}

__global__ void scan_local_k(int* __restrict__ data, int* __restrict__ bsums, int n) {
    __shared__ int tmp[1024];
    int i = blockIdx.x * 1024 + threadIdx.x;
    int v = (i < n) ? data[i] : 0;
    tmp[threadIdx.x] = v;
    __syncthreads();
    for (int off = 1; off < 1024; off <<= 1) {
        int t = (threadIdx.x >= off) ? tmp[threadIdx.x - off] : 0;
        __syncthreads();
        tmp[threadIdx.x] += t;
        __syncthreads();
    }
    if (i < n) data[i] = tmp[threadIdx.x] - v;   // exclusive, in place
    if (threadIdx.x == 1023) bsums[blockIdx.x] = tmp[1023];
}

__global__ void scan_top_k(int* __restrict__ bsums, int nbk) {
    __shared__ int tmp[512];
    int v = (threadIdx.x < nbk) ? bsums[threadIdx.x] : 0;
    tmp[threadIdx.x] = v;
    __syncthreads();
    for (int off = 1; off < 512; off <<= 1) {
        int t = (threadIdx.x >= off) ? tmp[threadIdx.x - off] : 0;
        __syncthreads();
        tmp[threadIdx.x] += t;
        __syncthreads();
    }
    if (threadIdx.x < nbk) bsums[threadIdx.x] = tmp[threadIdx.x] - v;  // exclusive
}

__global__ void add_offsets_k(int* __restrict__ data, const int* __restrict__ bsums, int n) {
    int i = blockIdx.x * 1024 + threadIdx.x;
    if (i < n) data[i] += bsums[blockIdx.x];
}

__global__ void bin_scatter_kernel(const int* __restrict__ ei, const float* __restrict__ ew,
                                   const int* __restrict__ scan_g, int2* __restrict__ rec_out,
                                   int n_edges, int nblk, int nb) {
    __shared__ int2 srec[EPB];               // 32 KB
    __shared__ unsigned short sbkt[EPB];     // 8 KB
    __shared__ int hist[NBMAX], loff[NBMAX], cur[NBMAX], gbase[NBMAX];  // 8 KB
    __shared__ int p[256];
    int tid = threadIdx.x, blk = blockIdx.x;
    int e0 = blk * EPB;
    int cnt = min(EPB, n_edges - e0);
    for (int i = tid; i < nb; i += 256) hist[i] = 0;
    __syncthreads();
#pragma unroll
    for (int j = 0; j < EPB / 256; ++j) {
        int e = e0 + tid + j * 256;
        if (e < n_edges) atomicAdd(&hist[ei[n_edges + e] >> 8], 1);
    }
    __syncthreads();
    int b0 = tid * 2;
    int c0 = (b0 < nb) ? hist[b0] : 0;
    int c1 = (b0 + 1 < nb) ? hist[b0 + 1] : 0;
    p[tid] = c0 + c1;
    __syncthreads();
    for (int off = 1; off < 256; off <<= 1) {
        int t = (tid >= off) ? p[tid - off] : 0;
        __syncthreads();
        p[tid] += t;
        __syncthreads();
    }
    int base = (tid > 0) ? p[tid - 1] : 0;
    if (b0 < nb)     { loff[b0] = base;          cur[b0] = base; }
    if (b0 + 1 < nb) { loff[b0 + 1] = base + c0; cur[b0 + 1] = base + c0; }
    for (int i = tid; i < nb; i += 256) gbase[i] = scan_g[i * nblk + blk];
    __syncthreads();
#pragma unroll
    for (int j = 0; j < EPB / 256; ++j) {
        int e = e0 + tid + j * 256;
        if (e < n_edges) {
            int s = ei[e], d = ei[n_edges + e];
            int b = d >> 8;
            int r = atomicAdd(&cur[b], 1);
            srec[r] = make_int2(s | ((d & 255) << 20), __float_as_int(ew[e]));
            sbkt[r] = (unsigned short)b;
        }
    }
    __syncthreads();
    for (int i = tid; i < cnt; i += 256) {
        int b = sbkt[i];
        rec_out[gbase[b] + (i - loff[b])] = srec[i];
    }
}

// ---------------- per-bucket node sort (-> full CSR + rowptr) ----------------

__global__ __launch_bounds__(256) void bucket_sort_kernel(
        const int2* __restrict__ rec_in, const int* __restrict__ scan_g,
        int2* __restrict__ rec_out, int* __restrict__ rowptr,
        int n_nodes, int n_edges, int nblk, int nb) {
    __shared__ int2 srec[CAP];               // 48 KB
    __shared__ int hist[256], cur[256], rp[256];
    int tid = threadIdx.x, b = blockIdx.x;
    int start = scan_g[b * nblk];
    int end = (b + 1 < nb) ? scan_g[(b + 1) * nblk] : n_edges;
    int cnt = end - start;
    hist[tid] = 0;
    __syncthreads();
    for (int i = tid; i < cnt; i += 256) {
        int2 r = rec_in[start + i];
        atomicAdd(&hist[(r.x >> 20) & 255], 1);
    }
    __syncthreads();
    int v = hist[tid];
    rp[tid] = v;
    __syncthreads();
    for (int off = 1; off < 256; off <<= 1) {
        int t = (tid >= off) ? rp[tid - off] : 0;
        __syncthreads();
        rp[tid] += t;
        __syncthreads();
    }
    int excl = rp[tid] - v;
    cur[tid] = excl;
    int node = (b << 8) + tid;
    if (node < n_nodes) rowptr[node] = start + excl;
    if (b == nb - 1 && tid == 0) rowptr[n_nodes] = n_edges;
    __syncthreads();
    for (int i = tid; i < cnt; i += 256) {
        int2 r = rec_in[start + i];
        int rk = atomicAdd(&cur[(r.x >> 20) & 255], 1);
        if (rk < CAP) srec[rk] = r;
    }
    __syncthreads();
    int lim = min(cnt, CAP);
    for (int i = tid; i < lim; i += 256) rec_out[start + i] = srec[i];
}

// ---------------- gather-side aggregation (wave-per-node, 4-wide ILP) ----------------

__global__ void gather1_kernel(const float* __restrict__ h1,
                               const int* __restrict__ rowptr,
                               const int2* __restrict__ rec,
                               float* __restrict__ agg, int n_nodes) {
    int n = blockIdx.x * 4 + (threadIdx.x >> 6);
    if (n >= n_nodes) return;
    int f = threadIdx.x & 63;
    int i = rowptr[n], end = rowptr[n + 1];
    float a0 = 0.f, a1 = 0.f, a2 = 0.f, a3 = 0.f;
    for (; i + 3 < end; i += 4) {
        int2 r0 = rec[i], r1 = rec[i + 1], r2 = rec[i + 2], r3 = rec[i + 3];
        a0 += h1[(size_t)(r0.x & 0xFFFFF) * 64 + f] * __int_as_float(r0.y);
        a1 += h1[(size_t)(r1.x & 0xFFFFF) * 64 + f] * __int_as_float(r1.y);
        a2 += h1[(size_t)(r2.x & 0xFFFFF) * 64 + f] * __int_as_float(r2.y);
        a3 += h1[(size_t)(r3.x & 0xFFFFF) * 64 + f] * __int_as_float(r3.y);
    }
    for (; i < end; ++i) {
        int2 r = rec[i];
        a0 += h1[(size_t)(r.x & 0xFFFFF) * 64 + f] * __int_as_float(r.y);
    }
    agg[(size_t)n * 64 + f] = fmaxf((a0 + a1) + (a2 + a3), 0.f);  // fused relu
}

__global__ void gather2_kernel(const float* __restrict__ h2,
                               const int* __restrict__ rowptr,
                               const int2* __restrict__ rec,
                               float* __restrict__ out, int n_nodes) {
    int n = blockIdx.x * 16 + (threadIdx.x >> 4);
    if (n >= n_nodes) return;
    int f = threadIdx.x & 15;
    int i = rowptr[n], end = rowptr[n + 1];
    float a0 = 0.f, a1 = 0.f, a2 = 0.f, a3 = 0.f;
    for (; i + 3 < end; i += 4) {
        int2 r0 = rec[i], r1 = rec[i + 1], r2 = rec[i + 2], r3 = rec[i + 3];
        a0 += h2[(size_t)(r0.x & 0xFFFFF) * 16 + f] * __int_as_float(r0.y);
        a1 += h2[(size_t)(r1.x & 0xFFFFF) * 16 + f] * __int_as_float(r1.y);
        a2 += h2[(size_t)(r2.x & 0xFFFFF) * 16 + f] * __int_as_float(r2.y);
        a3 += h2[(size_t)(r3.x & 0xFFFFF) * 16 + f] * __int_as_float(r3.y);
    }
    for (; i < end; ++i) {
        int2 r = rec[i];
        a0 += h2[(size_t)(r.x & 0xFFFFF) * 16 + f] * __int_as_float(r.y);
    }
    out[(size_t)n * 16 + f] = (a0 + a1) + (a2 + a3);
}

// ---------------- launch ----------------

extern "C" void kernel_launch(void* const* d_in, const int* in_sizes, int n_in,
                              void* d_out, int out_size, void* d_ws, size_t ws_size,
                              hipStream_t stream) {
    const float* x   = (const float*)d_in[0];
    const int*   ei1 = (const int*)d_in[1];
    const int*   ei2 = (const int*)d_in[2];
    const float* ew1 = (const float*)d_in[3];
    const float* ew2 = (const float*)d_in[4];
    const float* W1  = (const float*)d_in[5];
    const float* W2  = (const float*)d_in[6];

    const int n_nodes = in_sizes[0] / 128;          // 100000
    const int n_edges = in_sizes[1] / 2;            // 1600000
    const int nb   = (n_nodes + 255) >> 8;          // 391 buckets
    const int nblk = (n_edges + EPB - 1) / EPB;     // 391 binning blocks
    const int n_scan = nb * nblk;                   // 152881
    const int scan_blocks = (n_scan + 1023) / 1024; // 150

    // ws layout (4-byte units)
    float* h1     = (float*)d_ws;                        // N*64
    float* agg1   = h1 + (size_t)n_nodes * 64;           // N*64
    float* h2     = agg1 + (size_t)n_nodes * 64;         // N*16
    int2*  recbuf = (int2*)(h2 + (size_t)n_nodes * 16);  // E int2 (bucket-sorted)
    int2*  rec2   = recbuf + n_edges;                    // E int2 (node-sorted)
    int*   hist_g = (int*)(rec2 + n_edges);              // nb*nblk
    int*   bsums  = hist_g + n_scan;                     // 512
    int*   rowptr = bsums + 512;                         // N+1
    float* out    = (float*)d_out;

    // ---- layer 1 ----
    gemm1_kernel<<<(n_nodes + 127) / 128, 128, 0, stream>>>(x, W1, h1, n_nodes);
    bin_hist_kernel<<<nblk, 256, 0, stream>>>(ei1, hist_g, n_edges, nblk, nb);
    scan_local_k<<<scan_blocks, 1024, 0, stream>>>(hist_g, bsums, n_scan);
    scan_top_k<<<1, 512, 0, stream>>>(bsums, scan_blocks);
    add_offsets_k<<<scan_blocks, 1024, 0, stream>>>(hist_g, bsums, n_scan);
    bin_scatter_kernel<<<nblk, 256, 0, stream>>>(ei1, ew1, hist_g, recbuf, n_edges, nblk, nb);
    bucket_sort_kernel<<<nb, 256, 0, stream>>>(recbuf, hist_g, rec2, rowptr,
                                               n_nodes, n_edges, nblk, nb);
    gather1_kernel<<<(n_nodes + 3) / 4, 256, 0, stream>>>(h1, rowptr, rec2, agg1, n_nodes);

    // ---- layer 2 ----
    gemm2_kernel<<<(n_nodes + 127) / 128, 128, 0, stream>>>(agg1, W2, h2, n_nodes);
    bin_hist_kernel<<<nblk, 256, 0, stream>>>(ei2, hist_g, n_edges, nblk, nb);
    scan_local_k<<<scan_blocks, 1024, 0, stream>>>(hist_g, bsums, n_scan);
    scan_top_k<<<1, 512, 0, stream>>>(bsums, scan_blocks);
    add_offsets_k<<<scan_blocks, 1024, 0, stream>>>(hist_g, bsums, n_scan);
    bin_scatter_kernel<<<nblk, 256, 0, stream>>>(ei2, ew2, hist_g, recbuf, n_edges, nblk, nb);
    bucket_sort_kernel<<<nb, 256, 0, stream>>>(recbuf, hist_g, rec2, rowptr,
                                               n_nodes, n_edges, nblk, nb);
    gather2_kernel<<<(n_nodes + 15) / 16, 256, 0, stream>>>(h2, rowptr, rec2, out, n_nodes);
}

// Round 7
// 380.794 us; speedup vs baseline: 3.0031x; 1.0444x over previous
//
#include <hip/hip_runtime.h>
#include <hip/hip_bf16.h>

// GCN 2-layer, fp32 I/O. Pipeline per layer:
//   gemm (register-tiled) -> bin_hist/scan/bin_scatter (bucket-sort edges by dst>>8)
//        -> bucket_sort (in-LDS counting sort by dst&255 -> dst-sorted CSR + rowptr)
//        -> gather (wave-per-node, 4-wide ILP, no atomics)
// h1 kept as bf16 (halves gather-1 bandwidth; 12.8 MB table ~fits per-XCD L2).
// Record int2: .x = src | (dst&255)<<20, .y = bits of w.

#define EPB 4096     // edges per binning block
#define NBMAX 512    // max buckets (N <= 131072)
#define CAP 6144     // max records per bucket (avg 4096; 32-sigma headroom)

// ---------------- dense layers (register-tiled, k-major LDS) ----------------

// gemm1: [N,128] @ [128,64] -> bf16 [N,64]. 128 threads, tile 128n x 64f, thread 8x8.
__global__ __launch_bounds__(128) void gemm1_kernel(const float* __restrict__ x,
                                                    const float* __restrict__ W1,
                                                    __hip_bfloat16* __restrict__ h1,
                                                    int n_nodes) {
    __shared__ float As[32][132];   // k-major, node-contiguous; padded
    __shared__ float Bs[32][64];    // k-major, feat-contiguous
    int tid = threadIdx.x;
    int node0 = blockIdx.x * 128;
    int n8 = (tid & 15) * 8;
    int f8 = (tid >> 4) * 8;
    float acc[8][8];
#pragma unroll
    for (int i = 0; i < 8; ++i)
#pragma unroll
        for (int j = 0; j < 8; ++j) acc[i][j] = 0.f;

    const float4* x4 = reinterpret_cast<const float4*>(x);
    const float4* W4 = reinterpret_cast<const float4*>(W1);

    for (int s = 0; s < 4; ++s) {
#pragma unroll
        for (int j = 0; j < 8; ++j) {
            int idx = tid + j * 128;            // 1024 float4 = 128n x 32k
            int n = idx >> 3;
            int kq = idx & 7;
            float4 v = make_float4(0.f, 0.f, 0.f, 0.f);
            if (node0 + n < n_nodes) v = x4[(size_t)(node0 + n) * 32 + s * 8 + kq];
            int k4 = kq * 4;
            As[k4 + 0][n] = v.x;
            As[k4 + 1][n] = v.y;
            As[k4 + 2][n] = v.z;
            As[k4 + 3][n] = v.w;
        }
#pragma unroll
        for (int j = 0; j < 4; ++j) {
            int idx = tid + j * 128;            // 512 float4 = 32k x 64f
            int k = idx >> 4;
            int fq = idx & 15;
            *reinterpret_cast<float4*>(&Bs[k][fq * 4]) = W4[(size_t)(s * 32 + k) * 16 + fq];
        }
        __syncthreads();
#pragma unroll
        for (int kk = 0; kk < 32; ++kk) {
            float4 a0 = *reinterpret_cast<const float4*>(&As[kk][n8]);
            float4 a1 = *reinterpret_cast<const float4*>(&As[kk][n8 + 4]);
            float4 b0 = *reinterpret_cast<const float4*>(&Bs[kk][f8]);
            float4 b1 = *reinterpret_cast<const float4*>(&Bs[kk][f8 + 4]);
            float av[8] = {a0.x, a0.y, a0.z, a0.w, a1.x, a1.y, a1.z, a1.w};
            float bv[8] = {b0.x, b0.y, b0.z, b0.w, b1.x, b1.y, b1.z, b1.w};
#pragma unroll
            for (int i = 0; i < 8; ++i)
#pragma unroll
                for (int j = 0; j < 8; ++j) acc[i][j] += av[i] * bv[j];
        }
        __syncthreads();
    }
#pragma unroll
    for (int i = 0; i < 8; ++i) {
        int n = node0 + n8 + i;
        if (n < n_nodes) {
            __hip_bfloat16 tmp[8];
#pragma unroll
            for (int j = 0; j < 8; ++j) tmp[j] = __float2bfloat16(acc[i][j]);
            *reinterpret_cast<uint4*>(&h1[(size_t)n * 64 + f8]) =
                *reinterpret_cast<const uint4*>(tmp);
        }
    }
}

// gemm2: [N,64] @ [64,16] -> fp32 [N,16]. 128 threads, tile 128n x 16f, thread 4x4.
__global__ __launch_bounds__(128) void gemm2_kernel(const float* __restrict__ agg1,
                                                    const float* __restrict__ W2,
                                                    float* __restrict__ h2, int n_nodes) {
    __shared__ float As[32][132];
    __shared__ float Bs[32][16];
    int tid = threadIdx.x;
    int node0 = blockIdx.x * 128;
    int n4 = (tid & 31) * 4;
    int f4 = (tid >> 5) * 4;
    float acc[4][4];
#pragma unroll
    for (int i = 0; i < 4; ++i)
#pragma unroll
        for (int j = 0; j < 4; ++j) acc[i][j] = 0.f;

    const float4* a4 = reinterpret_cast<const float4*>(agg1);
    const float4* W4 = reinterpret_cast<const float4*>(W2);

    for (int s = 0; s < 2; ++s) {
#pragma unroll
        for (int j = 0; j < 8; ++j) {
            int idx = tid + j * 128;
            int n = idx >> 3;
            int kq = idx & 7;
            float4 v = make_float4(0.f, 0.f, 0.f, 0.f);
            if (node0 + n < n_nodes) v = a4[(size_t)(node0 + n) * 16 + s * 8 + kq];
            int k4 = kq * 4;
            As[k4 + 0][n] = v.x;
            As[k4 + 1][n] = v.y;
            As[k4 + 2][n] = v.z;
            As[k4 + 3][n] = v.w;
        }
        {
            int k = tid >> 2, fq = tid & 3;
            *reinterpret_cast<float4*>(&Bs[k][fq * 4]) = W4[(size_t)(s * 32 + k) * 4 + fq];
        }
        __syncthreads();
#pragma unroll
        for (int kk = 0; kk < 32; ++kk) {
            float4 a = *reinterpret_cast<const float4*>(&As[kk][n4]);
            float4 b = *reinterpret_cast<const float4*>(&Bs[kk][f4]);
            float av[4] = {a.x, a.y, a.z, a.w};
            float bv[4] = {b.x, b.y, b.z, b.w};
#pragma unroll
            for (int i = 0; i < 4; ++i)
#pragma unroll
                for (int j = 0; j < 4; ++j) acc[i][j] += av[i] * bv[j];
        }
        __syncthreads();
    }
#pragma unroll
    for (int i = 0; i < 4; ++i) {
        int n = node0 + n4 + i;
        if (n < n_nodes)
            *reinterpret_cast<float4*>(h2 + (size_t)n * 16 + f4) =
                make_float4(acc[i][0], acc[i][1], acc[i][2], acc[i][3]);
    }
}

// ---------------- edge binning (bucket = dst>>8) ----------------

__global__ void bin_hist_kernel(const int* __restrict__ ei, int* __restrict__ hist_g,
                                int n_edges, int nblk, int nb) {
    __shared__ int hist[NBMAX];
    int tid = threadIdx.x, blk = blockIdx.x;
    for (int i = tid; i < nb; i += 256) hist[i] = 0;
    __syncthreads();
    int e0 = blk * EPB;
#pragma unroll
    for (int j = 0; j < EPB / 256; ++j) {
        int e = e0 + tid + j * 256;
        if (e < n_edges) atomicAdd(&hist[ei[n_edges + e] >> 8], 1);
    }
    __syncthreads();
    for (int i = tid; i < nb; i += 256) hist_g[i * nblk + blk] = hist[i];  // bucket-major
}

__global__ void scan_local_k(int* __restrict__ data, int* __restrict__ bsums, int n) {
    __shared__ int tmp[1024];
    int i = blockIdx.x * 1024 + threadIdx.x;
    int v = (i < n) ? data[i] : 0;
    tmp[threadIdx.x] = v;
    __syncthreads();
    for (int off = 1; off < 1024; off <<= 1) {
        int t = (threadIdx.x >= off) ? tmp[threadIdx.x - off] : 0;
        __syncthreads();
        tmp[threadIdx.x] += t;
        __syncthreads();
    }
    if (i < n) data[i] = tmp[threadIdx.x] - v;   // exclusive, in place
    if (threadIdx.x == 1023) bsums[blockIdx.x] = tmp[1023];
}

__global__ void scan_top_k(int* __restrict__ bsums, int nbk) {
    __shared__ int tmp[512];
    int v = (threadIdx.x < nbk) ? bsums[threadIdx.x] : 0;
    tmp[threadIdx.x] = v;
    __syncthreads();
    for (int off = 1; off < 512; off <<= 1) {
        int t = (threadIdx.x >= off) ? tmp[threadIdx.x - off] : 0;
        __syncthreads();
        tmp[threadIdx.x] += t;
        __syncthreads();
    }
    if (threadIdx.x < nbk) bsums[threadIdx.x] = tmp[threadIdx.x] - v;  // exclusive
}

__global__ void add_offsets_k(int* __restrict__ data, const int* __restrict__ bsums, int n) {
    int i = blockIdx.x * 1024 + threadIdx.x;
    if (i < n) data[i] += bsums[blockIdx.x];
}

__global__ void bin_scatter_kernel(const int* __restrict__ ei, const float* __restrict__ ew,
                                   const int* __restrict__ scan_g, int2* __restrict__ rec_out,
                                   int n_edges, int nblk, int nb, int n_scan) {
    __shared__ int2 srec[EPB];               // 32 KB
    __shared__ unsigned short sbkt[EPB];     // 8 KB
    __shared__ int loff[NBMAX], cur[NBMAX], gbase[NBMAX];  // 6 KB
    __shared__ int p[256];
    int tid = threadIdx.x, blk = blockIdx.x;
    int e0 = blk * EPB;
    int cnt = min(EPB, n_edges - e0);
    // per-bucket counts for this block, reconstructed from adjacent scan entries
    // (scan is the exclusive scan of the flattened bucket-major count array)
    for (int i = tid; i < nb; i += 256) {
        int l = i * nblk + blk;
        int g = scan_g[l];
        int nxt = (l + 1 < n_scan) ? scan_g[l + 1] : n_edges;
        gbase[i] = g;
        loff[i] = nxt - g;                    // temporarily holds count
    }
    __syncthreads();
    // exclusive scan of counts -> loff (2 buckets/thread + Hillis-Steele over partials)
    int b0 = tid * 2;
    int c0 = (b0 < nb) ? loff[b0] : 0;
    int c1 = (b0 + 1 < nb) ? loff[b0 + 1] : 0;
    p[tid] = c0 + c1;
    __syncthreads();
    for (int off = 1; off < 256; off <<= 1) {
        int t = (tid >= off) ? p[tid - off] : 0;
        __syncthreads();
        p[tid] += t;
        __syncthreads();
    }
    int base = (tid > 0) ? p[tid - 1] : 0;
    __syncthreads();
    if (b0 < nb)     { loff[b0] = base;          cur[b0] = base; }
    if (b0 + 1 < nb) { loff[b0 + 1] = base + c0; cur[b0 + 1] = base + c0; }
    __syncthreads();
    // rank + stage (LDS counting sort by bucket)
#pragma unroll
    for (int j = 0; j < EPB / 256; ++j) {
        int e = e0 + tid + j * 256;
        if (e < n_edges) {
            int s = ei[e], d = ei[n_edges + e];
            int b = d >> 8;
            int r = atomicAdd(&cur[b], 1);
            srec[r] = make_int2(s | ((d & 255) << 20), __float_as_int(ew[e]));
            sbkt[r] = (unsigned short)b;
        }
    }
    __syncthreads();
    // coalesced run writes
    for (int i = tid; i < cnt; i += 256) {
        int b = sbkt[i];
        rec_out[gbase[b] + (i - loff[b])] = srec[i];
    }
}

// ---------------- per-bucket node sort (-> full CSR + rowptr) ----------------

__global__ __launch_bounds__(256) void bucket_sort_kernel(
        const int2* __restrict__ rec_in, const int* __restrict__ scan_g,
        int2* __restrict__ rec_out, int* __restrict__ rowptr,
        int n_nodes, int n_edges, int nblk, int nb) {
    __shared__ int2 srec[CAP];               // 48 KB
    __shared__ int hist[256], cur[256], rp[256];
    int tid = threadIdx.x, b = blockIdx.x;
    int start = scan_g[b * nblk];
    int end = (b + 1 < nb) ? scan_g[(b + 1) * nblk] : n_edges;
    int cnt = end - start;
    hist[tid] = 0;
    __syncthreads();
    for (int i = tid; i < cnt; i += 256) {
        int2 r = rec_in[start + i];
        atomicAdd(&hist[(r.x >> 20) & 255], 1);
    }
    __syncthreads();
    int v = hist[tid];
    rp[tid] = v;
    __syncthreads();
    for (int off = 1; off < 256; off <<= 1) {
        int t = (tid >= off) ? rp[tid - off] : 0;
        __syncthreads();
        rp[tid] += t;
        __syncthreads();
    }
    int excl = rp[tid] - v;
    cur[tid] = excl;
    int node = (b << 8) + tid;
    if (node < n_nodes) rowptr[node] = start + excl;
    if (b == nb - 1 && tid == 0) rowptr[n_nodes] = n_edges;
    __syncthreads();
    for (int i = tid; i < cnt; i += 256) {
        int2 r = rec_in[start + i];
        int rk = atomicAdd(&cur[(r.x >> 20) & 255], 1);
        if (rk < CAP) srec[rk] = r;
    }
    __syncthreads();
    int lim = min(cnt, CAP);
    for (int i = tid; i < lim; i += 256) rec_out[start + i] = srec[i];
}

// ---------------- gather-side aggregation (wave-per-node, 4-wide ILP) ----------------

__global__ void gather1_kernel(const __hip_bfloat16* __restrict__ h1,
                               const int* __restrict__ rowptr,
                               const int2* __restrict__ rec,
                               float* __restrict__ agg, int n_nodes) {
    int n = blockIdx.x * 4 + (threadIdx.x >> 6);
    if (n >= n_nodes) return;
    int f = threadIdx.x & 63;
    int i = rowptr[n], end = rowptr[n + 1];
    float a0 = 0.f, a1 = 0.f, a2 = 0.f, a3 = 0.f;
    for (; i + 3 < end; i += 4) {
        int2 r0 = rec[i], r1 = rec[i + 1], r2 = rec[i + 2], r3 = rec[i + 3];
        a0 += __bfloat162float(h1[(size_t)(r0.x & 0xFFFFF) * 64 + f]) * __int_as_float(r0.y);
        a1 += __bfloat162float(h1[(size_t)(r1.x & 0xFFFFF) * 64 + f]) * __int_as_float(r1.y);
        a2 += __bfloat162float(h1[(size_t)(r2.x & 0xFFFFF) * 64 + f]) * __int_as_float(r2.y);
        a3 += __bfloat162float(h1[(size_t)(r3.x & 0xFFFFF) * 64 + f]) * __int_as_float(r3.y);
    }
    for (; i < end; ++i) {
        int2 r = rec[i];
        a0 += __bfloat162float(h1[(size_t)(r.x & 0xFFFFF) * 64 + f]) * __int_as_float(r.y);
    }
    agg[(size_t)n * 64 + f] = fmaxf((a0 + a1) + (a2 + a3), 0.f);  // fused relu
}

__global__ void gather2_kernel(const float* __restrict__ h2,
                               const int* __restrict__ rowptr,
                               const int2* __restrict__ rec,
                               float* __restrict__ out, int n_nodes) {
    int n = blockIdx.x * 16 + (threadIdx.x >> 4);
    if (n >= n_nodes) return;
    int f = threadIdx.x & 15;
    int i = rowptr[n], end = rowptr[n + 1];
    float a0 = 0.f, a1 = 0.f, a2 = 0.f, a3 = 0.f;
    for (; i + 3 < end; i += 4) {
        int2 r0 = rec[i], r1 = rec[i + 1], r2 = rec[i + 2], r3 = rec[i + 3];
        a0 += h2[(size_t)(r0.x & 0xFFFFF) * 16 + f] * __int_as_float(r0.y);
        a1 += h2[(size_t)(r1.x & 0xFFFFF) * 16 + f] * __int_as_float(r1.y);
        a2 += h2[(size_t)(r2.x & 0xFFFFF) * 16 + f] * __int_as_float(r2.y);
        a3 += h2[(size_t)(r3.x & 0xFFFFF) * 16 + f] * __int_as_float(r3.y);
    }
    for (; i < end; ++i) {
        int2 r = rec[i];
        a0 += h2[(size_t)(r.x & 0xFFFFF) * 16 + f] * __int_as_float(r.y);
    }
    out[(size_t)n * 16 + f] = (a0 + a1) + (a2 + a3);
}

// ---------------- launch ----------------

extern "C" void kernel_launch(void* const* d_in, const int* in_sizes, int n_in,
                              void* d_out, int out_size, void* d_ws, size_t ws_size,
                              hipStream_t stream) {
    const float* x   = (const float*)d_in[0];
    const int*   ei1 = (const int*)d_in[1];
    const int*   ei2 = (const int*)d_in[2];
    const float* ew1 = (const float*)d_in[3];
    const float* ew2 = (const float*)d_in[4];
    const float* W1  = (const float*)d_in[5];
    const float* W2  = (const float*)d_in[6];

    const int n_nodes = in_sizes[0] / 128;          // 100000
    const int n_edges = in_sizes[1] / 2;            // 1600000
    const int nb   = (n_nodes + 255) >> 8;          // 391 buckets
    const int nblk = (n_edges + EPB - 1) / EPB;     // 391 binning blocks
    const int n_scan = nb * nblk;                   // 152881
    const int scan_blocks = (n_scan + 1023) / 1024; // 150

    // ws layout (4-byte units)
    __hip_bfloat16* h1 = (__hip_bfloat16*)d_ws;          // N*64 bf16 = N*32 floats
    float* agg1   = (float*)d_ws + (size_t)n_nodes * 32; // N*64
    float* h2     = agg1 + (size_t)n_nodes * 64;         // N*16
    int2*  recbuf = (int2*)(h2 + (size_t)n_nodes * 16);  // E int2 (bucket-sorted)
    int2*  rec2   = recbuf + n_edges;                    // E int2 (node-sorted)
    int*   hist_g = (int*)(rec2 + n_edges);              // nb*nblk
    int*   bsums  = hist_g + n_scan;                     // 512
    int*   rowptr = bsums + 512;                         // N+1
    float* out    = (float*)d_out;

    // ---- layer 1 ----
    gemm1_kernel<<<(n_nodes + 127) / 128, 128, 0, stream>>>(x, W1, h1, n_nodes);
    bin_hist_kernel<<<nblk, 256, 0, stream>>>(ei1, hist_g, n_edges, nblk, nb);
    scan_local_k<<<scan_blocks, 1024, 0, stream>>>(hist_g, bsums, n_scan);
    scan_top_k<<<1, 512, 0, stream>>>(bsums, scan_blocks);
    add_offsets_k<<<scan_blocks, 1024, 0, stream>>>(hist_g, bsums, n_scan);
    bin_scatter_kernel<<<nblk, 256, 0, stream>>>(ei1, ew1, hist_g, recbuf, n_edges, nblk, nb, n_scan);
    bucket_sort_kernel<<<nb, 256, 0, stream>>>(recbuf, hist_g, rec2, rowptr,
                                               n_nodes, n_edges, nblk, nb);
    gather1_kernel<<<(n_nodes + 3) / 4, 256, 0, stream>>>(h1, rowptr, rec2, agg1, n_nodes);

    // ---- layer 2 ----
    gemm2_kernel<<<(n_nodes + 127) / 128, 128, 0, stream>>>(agg1, W2, h2, n_nodes);
    bin_hist_kernel<<<nblk, 256, 0, stream>>>(ei2, hist_g, n_edges, nblk, nb);
    scan_local_k<<<scan_blocks, 1024, 0, stream>>>(hist_g, bsums, n_scan);
    scan_top_k<<<1, 512, 0, stream>>>(bsums, scan_blocks);
    add_offsets_k<<<scan_blocks, 1024, 0, stream>>>(hist_g, bsums, n_scan);
    bin_scatter_kernel<<<nblk, 256, 0, stream>>>(ei2, ew2, hist_g, recbuf, n_edges, nblk, nb, n_scan);
    bucket_sort_kernel<<<nb, 256, 0, stream>>>(recbuf, hist_g, rec2, rowptr,
                                               n_nodes, n_edges, nblk, nb);
    gather2_kernel<<<(n_nodes + 15) / 16, 256, 0, stream>>>(h2, rowptr, rec2, out, n_nodes);
}